// Round 8
// baseline (213.988 us; speedup 1.0000x reference)
//
#include <hip/hip_runtime.h>
#include <stdint.h>

// Problem constants (B=2, T=1024 -> N=2048 tokens; D=H=1024; E=8; top-2)
#define D_DIM 1024
#define H_DIM 1024
#define NE 8
#define NTOK 2048
#define SB 4608            // shared-expert slot base (expert slots padded to 64 fit in 4608)
#define TOTAL_ROWS 6656    // 4608 + 2048
#define MAXSLOT 104        // max 64-row tiles: <=72 expert + 32 shared

typedef __bf16 bf16;
typedef bf16 bf16x8 __attribute__((ext_vector_type(8)));
typedef float f32x4 __attribute__((ext_vector_type(4)));

// ---- workspace layout (bytes) ----
#define WS_NTILES     0
#define WS_TILE_E     64          // 128 ints
#define WS_TILE_BASE  576         // 128 ints
#define WS_EIDX       2048        // 4096 ints
#define WS_WTOK       18432      // 4096 floats
#define WS_TOK        34816      // 7168 ints
#define WS_SLOT       63488      // 4096 ints
#define WS_XG         131072     // 7168*1024 bf16; GEMM1 input, then reused as eo (GEMM2 out)
#define WS_HID        16777216   // 7168*1024 bf16
#define WS_W1B        33554432   // 16 MB
#define WS_W2B        50331648   // 16 MB
#define WS_CFCB       67108864   // 2 MB
#define WS_CPROJB     69206016   // 2 MB (end 71,303,168)

// ---- fused: blocks [0,512) run the router (4 tokens/block, wave per token);
//      blocks [512, 9728) convert the 18M fp32 weight elements to bf16. ----
#define M1 (8 * 1024 * 1024)
#define M2 (16 * 1024 * 1024)
#define M3 (17 * 1024 * 1024)
__global__ __launch_bounds__(256) void convrouter(
    const float* __restrict__ x, const float* __restrict__ gw,
    const float* __restrict__ lb, int* __restrict__ eidx,
    float* __restrict__ wtok, bf16* __restrict__ xg,
    const float* __restrict__ w1, const float* __restrict__ w2,
    const float* __restrict__ cfc, const float* __restrict__ cproj,
    bf16* __restrict__ w1b, bf16* __restrict__ w2b, bf16* __restrict__ cfcb,
    bf16* __restrict__ cprojb) {
  const int bx = blockIdx.x;
  if (bx >= 512) {
    // ---- weight conversion path ----
    int i = ((bx - 512) * 256 + threadIdx.x) * 8;
    const float* s;
    bf16* d;
    if (i < M1)      { s = w1 + i;           d = w1b + i; }
    else if (i < M2) { s = w2 + (i - M1);    d = w2b + (i - M1); }
    else if (i < M3) { s = cfc + (i - M2);   d = cfcb + (i - M2); }
    else             { s = cproj + (i - M3); d = cprojb + (i - M3); }
    float4 a = *(const float4*)(s);
    float4 b = *(const float4*)(s + 4);
    union { uint4 v; bf16 h[8]; } t;
    t.h[0] = (bf16)a.x; t.h[1] = (bf16)a.y; t.h[2] = (bf16)a.z; t.h[3] = (bf16)a.w;
    t.h[4] = (bf16)b.x; t.h[5] = (bf16)b.y; t.h[6] = (bf16)b.z; t.h[7] = (bf16)b.w;
    *(uint4*)(d) = t.v;
    return;
  }
  // ---- router path ----
  const int wave = threadIdx.x >> 6;
  const int lane = threadIdx.x & 63;
  const int n = bx * 4 + wave;

  const float4* xr = (const float4*)(x + (size_t)n * D_DIM);
  float4 xv[4];
#pragma unroll
  for (int q = 0; q < 4; q++) xv[q] = xr[q * 64 + lane];

  float acc[NE];
#pragma unroll
  for (int e = 0; e < NE; e++) acc[e] = 0.f;
#pragma unroll
  for (int e = 0; e < NE; e++) {
    const float4* gr = (const float4*)(gw + e * D_DIM);
#pragma unroll
    for (int q = 0; q < 4; q++) {
      float4 g = gr[q * 64 + lane];
      acc[e] += xv[q].x * g.x + xv[q].y * g.y + xv[q].z * g.z + xv[q].w * g.w;
    }
  }

  bf16* dst = xg + (size_t)n * D_DIM;
#pragma unroll
  for (int q = 0; q < 4; q++) {
    union { ushort4 u; bf16 h[4]; } t;
    t.h[0] = (bf16)xv[q].x; t.h[1] = (bf16)xv[q].y;
    t.h[2] = (bf16)xv[q].z; t.h[3] = (bf16)xv[q].w;
    *(ushort4*)(dst + (q * 64 + lane) * 4) = t.u;
  }

#pragma unroll
  for (int e = 0; e < NE; e++)
#pragma unroll
    for (int off = 32; off > 0; off >>= 1) acc[e] += __shfl_xor(acc[e], off, 64);

  if (lane == 0) {
    float b[NE];
#pragma unroll
    for (int e = 0; e < NE; e++) b[e] = acc[e] + lb[e];
    int i0 = 0; float v0 = b[0];
#pragma unroll
    for (int e = 1; e < NE; e++) if (b[e] > v0) { v0 = b[e]; i0 = e; }
    int i1 = -1; float v1 = -3.4e38f;
#pragma unroll
    for (int e = 0; e < NE; e++) if (e != i0 && b[e] > v1) { v1 = b[e]; i1 = e; }
    float s0 = 1.f / (1.f + expf(-acc[i0]));
    float s1 = 1.f / (1.f + expf(-acc[i1]));
    float s = s0 + s1 + 1e-6f;
    eidx[n * 2] = i0;     wtok[n * 2] = s0 / s;
    eidx[n * 2 + 1] = i1; wtok[n * 2 + 1] = s1 / s;
  }
}

// ---- assign: single block. Ballot-aggregated per-expert positions, 64-row
// tile table, tok table, token->slot map. ----
__global__ __launch_bounds__(256) void assign_kernel(
    const int* __restrict__ eidx, int* __restrict__ tE, int* __restrict__ tB,
    int* __restrict__ ntiles, int* __restrict__ tok,
    int* __restrict__ slotIdx) {
  __shared__ int segCnt[64][NE];
  __shared__ int segBase[64][NE];
  const int tid = threadIdx.x;
  const int wave = tid >> 6, lane = tid & 63;
  const unsigned long long below = (lane == 0) ? 0ull : ((~0ull) >> (64 - lane));

  int e16[16], pr16[16];
#pragma unroll
  for (int t = 0; t < 16; t++) {
    const int r = t * 256 + tid;
    const int seg = t * 4 + wave;
    const int e = eidx[r];
    int prior = 0;
#pragma unroll
    for (int ee = 0; ee < NE; ee++) {
      unsigned long long m = __ballot(e == ee);
      if (e == ee) prior = __popcll(m & below);
      if (lane == ee) segCnt[seg][ee] = __popcll(m);
    }
    e16[t] = e; pr16[t] = prior;
  }

  // tok init: pads -> token 0; shared region -> identity
  for (int s = tid; s < TOTAL_ROWS; s += 256) {
    tok[s] = (s < SB) ? 0 : (s - SB);
  }
  __syncthreads();

  if (wave == 0) {
    int v[NE], inc[NE];
#pragma unroll
    for (int e = 0; e < NE; e++) { v[e] = segCnt[lane][e]; inc[e] = v[e]; }
#pragma unroll
    for (int off = 1; off < 64; off <<= 1) {
#pragma unroll
      for (int e = 0; e < NE; e++) {
        int u = __shfl_up(inc[e], off);
        if (lane >= off) inc[e] += u;
      }
    }
    int tot[NE];
#pragma unroll
    for (int e = 0; e < NE; e++) tot[e] = __shfl(inc[e], 63);
    int offsL[NE]; int b = 0;
#pragma unroll
    for (int e = 0; e < NE; e++) { offsL[e] = b; b += ((tot[e] + 63) >> 6) << 6; }
#pragma unroll
    for (int e = 0; e < NE; e++) segBase[lane][e] = offsL[e] + (inc[e] - v[e]);
    if (lane == 0) {
      int nt = 0;
      for (int e = 0; e < NE; e++) {
        int t64 = (tot[e] + 63) >> 6;
        for (int t = 0; t < t64; t++) { tE[nt] = e; tB[nt] = offsL[e] + t * 64; nt++; }
      }
      for (int t = 0; t < 32; t++) { tE[nt] = NE; tB[nt] = SB + t * 64; nt++; }
      ntiles[0] = nt;
    }
  }
  __syncthreads();

#pragma unroll
  for (int t = 0; t < 16; t++) {
    const int r = t * 256 + tid;
    const int seg = t * 4 + wave;
    const int slot = segBase[seg][e16[t]] + pr16[t];
    tok[slot] = r >> 1;
    slotIdx[r] = slot;
  }
}

// ---- table-driven 64x64 bf16 GEMM (C = A·B^T), BK=32, double-buffered LDS,
// VGPR-roundtrip staging pipeline (depth 2): global loads land in VGPRs and a
// ds_write_b128 publishes them ONE ITERATION LATER, so the barrier only waits
// lgkmcnt -- next tile's global loads remain in flight ACROSS the barrier
// (impossible with global_load_lds, whose outstanding loads force a vmcnt(0)
// drain at __syncthreads). Iter k: ds_write(tile k+1 regs) -> load(tile k+2
// -> regs) -> compute(tile k) -> barrier. Bank conflicts: XOR chunk swizzle
// (4 slots ^ (row>>1)&3) -> 2-way max (free, m136). 4 waves, each 32x32.
// MODE 0: A gathered via tok[] from xg; relu^2 -> bf16 store to hid.
// MODE 1: A direct from hid; plain bf16 store to eo (slot space). ----
template <int MODE>
__global__ __launch_bounds__(256) void moe_gemm(
    const bf16* __restrict__ Ab, const bf16* __restrict__ We,
    const bf16* __restrict__ Ws, const int* __restrict__ tE,
    const int* __restrict__ tB, const int* __restrict__ ntp,
    bf16* __restrict__ Cout, const int* __restrict__ tok) {
  const int mslot = blockIdx.x;
  if (mslot >= ntp[0]) return;
  const int e = tE[mslot];
  const int base = tB[mslot];
  const bf16* Bp = (e < NE) ? (We + (size_t)e * (H_DIM * D_DIM)) : Ws;
  const int n0 = blockIdx.y * 64;

  __shared__ bf16 As[2 * 2048];   // 2 x 64x32 bf16 = 8 KB
  __shared__ bf16 Bs[2 * 2048];   // 2 x 64x32 bf16 = 8 KB

  const int tid = threadIdx.x;
  const int wave = tid >> 6, lane = tid & 63;

  // staging: row tid>>2 (0..63), chunk slot tid&3; source chunk XOR-swizzled
  const int rS = tid >> 2, sS = tid & 3;
  const int swz = (sS ^ ((rS >> 1) & 3)) * 8;
  const bf16* gA;
  if (MODE == 0) gA = Ab + (size_t)tok[base + rS] * 1024 + swz;
  else           gA = Ab + (size_t)(base + rS) * 1024 + swz;
  const bf16* gB = Bp + (size_t)(n0 + rS) * 1024 + swz;
  const int dst8 = tid * 8;       // lane-contiguous 16B LDS dest

  const int wm = (wave >> 1) * 32, wn = (wave & 1) * 32;
  const int fr = lane & 15, chk = lane >> 4;
  int aOff[2], bOff[2];
#pragma unroll
  for (int i = 0; i < 2; i++) {
    const int r = wm + i * 16 + fr;
    aOff[i] = r * 32 + ((chk ^ ((r >> 1) & 3)) * 8);
  }
#pragma unroll
  for (int j = 0; j < 2; j++) {
    const int r = wn + j * 16 + fr;
    bOff[j] = r * 32 + ((chk ^ ((r >> 1) & 3)) * 8);
  }

  const f32x4 zero = {0.f, 0.f, 0.f, 0.f};
  f32x4 acc[2][2];
#pragma unroll
  for (int i = 0; i < 2; i++)
#pragma unroll
    for (int j = 0; j < 2; j++) acc[i][j] = zero;

  // prologue: tile 0 -> regs -> LDS[0]; tile 1 -> regs (in flight across barrier)
  uint4 rA = *(const uint4*)gA;
  uint4 rB = *(const uint4*)gB;
  *(uint4*)(As + dst8) = rA;
  *(uint4*)(Bs + dst8) = rB;
  rA = *(const uint4*)(gA + 32);
  rB = *(const uint4*)(gB + 32);
  __syncthreads();

  for (int kt = 0; kt < 32; ++kt) {
    const int cur = kt & 1;
    // publish tile kt+1 (regs loaded one iteration ago) into the free buffer
    if (kt + 1 < 32) {
      *(uint4*)(As + (cur ^ 1) * 2048 + dst8) = rA;
      *(uint4*)(Bs + (cur ^ 1) * 2048 + dst8) = rB;
    }
    // issue tile kt+2 loads; they fly across the barrier below
    if (kt + 2 < 32) {
      rA = *(const uint4*)(gA + (kt + 2) * 32);
      rB = *(const uint4*)(gB + (kt + 2) * 32);
    }
    bf16x8 af[2], bfv[2];
#pragma unroll
    for (int i = 0; i < 2; i++) af[i] = *(const bf16x8*)&As[cur * 2048 + aOff[i]];
#pragma unroll
    for (int j = 0; j < 2; j++) bfv[j] = *(const bf16x8*)&Bs[cur * 2048 + bOff[j]];
#pragma unroll
    for (int i = 0; i < 2; i++)
#pragma unroll
      for (int j = 0; j < 2; j++)
        acc[i][j] = __builtin_amdgcn_mfma_f32_16x16x32_bf16(af[i], bfv[j],
                                                            acc[i][j], 0, 0, 0);
    __syncthreads();  // lgkm only: ds_writes visible, reads of LDS[cur] done
  }

  const int rbase = (lane >> 4) * 4;
#pragma unroll
  for (int i = 0; i < 2; i++) {
#pragma unroll
    for (int j = 0; j < 2; j++) {
      const int col = n0 + wn + j * 16 + fr;
#pragma unroll
      for (int r = 0; r < 4; r++) {
        const int orow = wm + i * 16 + rbase + r;
        float v = acc[i][j][r];
        if (MODE == 0) v = v > 0.f ? v * v : 0.f;
        Cout[(size_t)(base + orow) * 1024 + col] = (bf16)v;
      }
    }
  }
}

// ---- combine: out[t] = w0*eo[s0] + w1*eo[s1] + eo[SB+t]. One block/token. ----
__global__ __launch_bounds__(256) void combine_kernel(
    const bf16* __restrict__ eo, const int* __restrict__ slotIdx,
    const float* __restrict__ wtok, float* __restrict__ out) {
  const int t = blockIdx.x;
  const int c = threadIdx.x * 4;
  const int s0 = slotIdx[t * 2], s1 = slotIdx[t * 2 + 1];
  const float w0 = wtok[t * 2], w1 = wtok[t * 2 + 1];
  union U { uint2 v; bf16 h[4]; };
  U a, b, sh;
  a.v  = *(const uint2*)(eo + (size_t)s0 * 1024 + c);
  b.v  = *(const uint2*)(eo + (size_t)s1 * 1024 + c);
  sh.v = *(const uint2*)(eo + (size_t)(SB + t) * 1024 + c);
  float4 o;
  o.x = w0 * (float)a.h[0] + w1 * (float)b.h[0] + (float)sh.h[0];
  o.y = w0 * (float)a.h[1] + w1 * (float)b.h[1] + (float)sh.h[1];
  o.z = w0 * (float)a.h[2] + w1 * (float)b.h[2] + (float)sh.h[2];
  o.w = w0 * (float)a.h[3] + w1 * (float)b.h[3] + (float)sh.h[3];
  *(float4*)(out + (size_t)t * 1024 + c) = o;
}

extern "C" void kernel_launch(void* const* d_in, const int* in_sizes, int n_in,
                              void* d_out, int out_size, void* d_ws,
                              size_t ws_size, hipStream_t stream) {
  const float* x     = (const float*)d_in[0];
  const float* gw    = (const float*)d_in[1];
  const float* lb    = (const float*)d_in[2];
  const float* w1    = (const float*)d_in[3];
  const float* w2    = (const float*)d_in[4];
  const float* cfc   = (const float*)d_in[5];
  const float* cproj = (const float*)d_in[6];
  float* out = (float*)d_out;
  char* ws = (char*)d_ws;

  int*   ntl   = (int*)(ws + WS_NTILES);
  int*   tE    = (int*)(ws + WS_TILE_E);
  int*   tB    = (int*)(ws + WS_TILE_BASE);
  int*   eidx  = (int*)(ws + WS_EIDX);
  float* wtok  = (float*)(ws + WS_WTOK);
  int*   tok   = (int*)(ws + WS_TOK);
  int*   slotI = (int*)(ws + WS_SLOT);
  bf16*  xg    = (bf16*)(ws + WS_XG);     // GEMM1 input; reused as eo for GEMM2 out
  bf16*  hid   = (bf16*)(ws + WS_HID);
  bf16*  w1b   = (bf16*)(ws + WS_W1B);
  bf16*  w2b   = (bf16*)(ws + WS_W2B);
  bf16*  cfcb  = (bf16*)(ws + WS_CFCB);
  bf16*  cprojb= (bf16*)(ws + WS_CPROJB);

  convrouter<<<9728, 256, 0, stream>>>(x, gw, lb, eidx, wtok, xg,
                                       w1, w2, cfc, cproj,
                                       w1b, w2b, cfcb, cprojb);
  assign_kernel<<<1, 256, 0, stream>>>(eidx, tE, tB, ntl, tok, slotI);

  moe_gemm<0><<<dim3(MAXSLOT, 16), 256, 0, stream>>>(
      xg, w1b, cfcb, tE, tB, ntl, hid, tok);
  moe_gemm<1><<<dim3(MAXSLOT, 16), 256, 0, stream>>>(
      hid, w2b, cprojb, tE, tB, ntl, xg, tok);
  combine_kernel<<<NTOK, 256, 0, stream>>>(xg, slotI, wtok, out);
}

// Round 9
// 201.362 us; speedup vs baseline: 1.0627x; 1.0627x over previous
//
#include <hip/hip_runtime.h>
#include <stdint.h>

// Problem constants (B=2, T=1024 -> N=2048 tokens; D=H=1024; E=8; top-2)
#define D_DIM 1024
#define H_DIM 1024
#define NE 8
#define NTOK 2048
#define SB 4608            // shared-expert slot base (expert slots padded to 64 fit in 4608)
#define TOTAL_ROWS 6656    // 4608 + 2048
#define MAXSLOT 104        // max 64-row tiles: <=72 expert + 32 shared
#define GEMM_GRID 1664     // 8 XCD groups x 208 max pairs per group

typedef __bf16 bf16;
typedef bf16 bf16x8 __attribute__((ext_vector_type(8)));
typedef float f32x4 __attribute__((ext_vector_type(4)));

// ---- workspace layout (bytes) ----
#define WS_NTILES     0           // [0]=ntiles, [1]=pairs per XCD group
#define WS_TILE_E     64          // 128 ints
#define WS_TILE_BASE  576         // 128 ints
#define WS_EIDX       2048        // 4096 ints
#define WS_WTOK       18432      // 4096 floats
#define WS_TOK        34816      // 7168 ints
#define WS_SLOT       63488      // 4096 ints
#define WS_XG         131072     // 7168*1024 bf16; GEMM1 input, then reused as eo (GEMM2 out)
#define WS_HID        16777216   // 7168*1024 bf16
#define WS_W1B        33554432   // 16 MB
#define WS_W2B        50331648   // 16 MB
#define WS_CFCB       67108864   // 2 MB
#define WS_CPROJB     69206016   // 2 MB (end 71,303,168)

// ---- fused: blocks [0,512) run the router (4 tokens/block, wave per token);
//      blocks [512, 9728) convert the 18M fp32 weight elements to bf16. ----
#define M1 (8 * 1024 * 1024)
#define M2 (16 * 1024 * 1024)
#define M3 (17 * 1024 * 1024)
__global__ __launch_bounds__(256) void convrouter(
    const float* __restrict__ x, const float* __restrict__ gw,
    const float* __restrict__ lb, int* __restrict__ eidx,
    float* __restrict__ wtok, bf16* __restrict__ xg,
    const float* __restrict__ w1, const float* __restrict__ w2,
    const float* __restrict__ cfc, const float* __restrict__ cproj,
    bf16* __restrict__ w1b, bf16* __restrict__ w2b, bf16* __restrict__ cfcb,
    bf16* __restrict__ cprojb) {
  const int bx = blockIdx.x;
  if (bx >= 512) {
    // ---- weight conversion path ----
    int i = ((bx - 512) * 256 + threadIdx.x) * 8;
    const float* s;
    bf16* d;
    if (i < M1)      { s = w1 + i;           d = w1b + i; }
    else if (i < M2) { s = w2 + (i - M1);    d = w2b + (i - M1); }
    else if (i < M3) { s = cfc + (i - M2);   d = cfcb + (i - M2); }
    else             { s = cproj + (i - M3); d = cprojb + (i - M3); }
    float4 a = *(const float4*)(s);
    float4 b = *(const float4*)(s + 4);
    union { uint4 v; bf16 h[8]; } t;
    t.h[0] = (bf16)a.x; t.h[1] = (bf16)a.y; t.h[2] = (bf16)a.z; t.h[3] = (bf16)a.w;
    t.h[4] = (bf16)b.x; t.h[5] = (bf16)b.y; t.h[6] = (bf16)b.z; t.h[7] = (bf16)b.w;
    *(uint4*)(d) = t.v;
    return;
  }
  // ---- router path ----
  const int wave = threadIdx.x >> 6;
  const int lane = threadIdx.x & 63;
  const int n = bx * 4 + wave;

  const float4* xr = (const float4*)(x + (size_t)n * D_DIM);
  float4 xv[4];
#pragma unroll
  for (int q = 0; q < 4; q++) xv[q] = xr[q * 64 + lane];

  float acc[NE];
#pragma unroll
  for (int e = 0; e < NE; e++) acc[e] = 0.f;
#pragma unroll
  for (int e = 0; e < NE; e++) {
    const float4* gr = (const float4*)(gw + e * D_DIM);
#pragma unroll
    for (int q = 0; q < 4; q++) {
      float4 g = gr[q * 64 + lane];
      acc[e] += xv[q].x * g.x + xv[q].y * g.y + xv[q].z * g.z + xv[q].w * g.w;
    }
  }

  bf16* dst = xg + (size_t)n * D_DIM;
#pragma unroll
  for (int q = 0; q < 4; q++) {
    union { ushort4 u; bf16 h[4]; } t;
    t.h[0] = (bf16)xv[q].x; t.h[1] = (bf16)xv[q].y;
    t.h[2] = (bf16)xv[q].z; t.h[3] = (bf16)xv[q].w;
    *(ushort4*)(dst + (q * 64 + lane) * 4) = t.u;
  }

#pragma unroll
  for (int e = 0; e < NE; e++)
#pragma unroll
    for (int off = 32; off > 0; off >>= 1) acc[e] += __shfl_xor(acc[e], off, 64);

  if (lane == 0) {
    float b[NE];
#pragma unroll
    for (int e = 0; e < NE; e++) b[e] = acc[e] + lb[e];
    int i0 = 0; float v0 = b[0];
#pragma unroll
    for (int e = 1; e < NE; e++) if (b[e] > v0) { v0 = b[e]; i0 = e; }
    int i1 = -1; float v1 = -3.4e38f;
#pragma unroll
    for (int e = 0; e < NE; e++) if (e != i0 && b[e] > v1) { v1 = b[e]; i1 = e; }
    float s0 = 1.f / (1.f + expf(-acc[i0]));
    float s1 = 1.f / (1.f + expf(-acc[i1]));
    float s = s0 + s1 + 1e-6f;
    eidx[n * 2] = i0;     wtok[n * 2] = s0 / s;
    eidx[n * 2 + 1] = i1; wtok[n * 2 + 1] = s1 / s;
  }
}

// ---- assign: single block. Ballot-aggregated per-expert positions, 64-row
// tile table, tok table, token->slot map, XCD partition size. ----
__global__ __launch_bounds__(256) void assign_kernel(
    const int* __restrict__ eidx, int* __restrict__ tE, int* __restrict__ tB,
    int* __restrict__ ntiles, int* __restrict__ tok,
    int* __restrict__ slotIdx) {
  __shared__ int segCnt[64][NE];
  __shared__ int segBase[64][NE];
  const int tid = threadIdx.x;
  const int wave = tid >> 6, lane = tid & 63;
  const unsigned long long below = (lane == 0) ? 0ull : ((~0ull) >> (64 - lane));

  int e16[16], pr16[16];
#pragma unroll
  for (int t = 0; t < 16; t++) {
    const int r = t * 256 + tid;
    const int seg = t * 4 + wave;
    const int e = eidx[r];
    int prior = 0;
#pragma unroll
    for (int ee = 0; ee < NE; ee++) {
      unsigned long long m = __ballot(e == ee);
      if (e == ee) prior = __popcll(m & below);
      if (lane == ee) segCnt[seg][ee] = __popcll(m);
    }
    e16[t] = e; pr16[t] = prior;
  }

  // tok init: pads -> token 0; shared region -> identity
  for (int s = tid; s < TOTAL_ROWS; s += 256) {
    tok[s] = (s < SB) ? 0 : (s - SB);
  }
  __syncthreads();

  if (wave == 0) {
    int v[NE], inc[NE];
#pragma unroll
    for (int e = 0; e < NE; e++) { v[e] = segCnt[lane][e]; inc[e] = v[e]; }
#pragma unroll
    for (int off = 1; off < 64; off <<= 1) {
#pragma unroll
      for (int e = 0; e < NE; e++) {
        int u = __shfl_up(inc[e], off);
        if (lane >= off) inc[e] += u;
      }
    }
    int tot[NE];
#pragma unroll
    for (int e = 0; e < NE; e++) tot[e] = __shfl(inc[e], 63);
    int offsL[NE]; int b = 0;
#pragma unroll
    for (int e = 0; e < NE; e++) { offsL[e] = b; b += ((tot[e] + 63) >> 6) << 6; }
#pragma unroll
    for (int e = 0; e < NE; e++) segBase[lane][e] = offsL[e] + (inc[e] - v[e]);
    if (lane == 0) {
      int nt = 0;
      for (int e = 0; e < NE; e++) {
        int t64 = (tot[e] + 63) >> 6;
        for (int t = 0; t < t64; t++) { tE[nt] = e; tB[nt] = offsL[e] + t * 64; nt++; }
      }
      for (int t = 0; t < 32; t++) { tE[nt] = NE; tB[nt] = SB + t * 64; nt++; }
      ntiles[0] = nt;
      ntiles[1] = (nt * 16 + 7) >> 3;   // pairs per XCD group (ceil(nt*16/8))
    }
  }
  __syncthreads();

#pragma unroll
  for (int t = 0; t < 16; t++) {
    const int r = t * 256 + tid;
    const int seg = t * 4 + wave;
    const int slot = segBase[seg][e16[t]] + pr16[t];
    tok[slot] = r >> 1;
    slotIdx[r] = slot;
  }
}

// ---- table-driven 64x64 bf16 GEMM (C = A·B^T), BK=32, double-buffered LDS,
// VGPR-roundtrip staging pipeline (depth 2): loads -> VGPRs, ds_write one iter
// later, so next tile's global loads stay in flight across the (lgkm-only)
// barrier. XCD-AWARE PARTITION: 1-D grid; bid%8 = XCD slot (round-robin
// dispatch heuristic); each XCD group takes a contiguous chunk of the
// expert-sorted (mslot,n0) pair list, so each XCD's ~2 experts' weights
// (~4 MB) fit its private L2 -> weight re-reads become L2 hits that the
// 1-iter prefetch flight can hide. Bank conflicts: XOR chunk swizzle -> 0.
// MODE 0: A gathered via tok[] from xg; relu^2 -> bf16 store to hid.
// MODE 1: A direct from hid; plain bf16 store to eo (slot space). ----
template <int MODE>
__global__ __launch_bounds__(256) void moe_gemm(
    const bf16* __restrict__ Ab, const bf16* __restrict__ We,
    const bf16* __restrict__ Ws, const int* __restrict__ tE,
    const int* __restrict__ tB, const int* __restrict__ ntp,
    bf16* __restrict__ Cout, const int* __restrict__ tok) {
  const int per = ntp[1];
  const int g = blockIdx.x & 7, idx = blockIdx.x >> 3;
  const int p = g * per + idx;
  if (idx >= per || p >= ntp[0] * 16) return;
  const int mslot = p >> 4;
  const int n0 = (p & 15) * 64;
  const int e = tE[mslot];
  const int base = tB[mslot];
  const bf16* Bp = (e < NE) ? (We + (size_t)e * (H_DIM * D_DIM)) : Ws;

  __shared__ bf16 As[2 * 2048];   // 2 x 64x32 bf16 = 8 KB
  __shared__ bf16 Bs[2 * 2048];   // 2 x 64x32 bf16 = 8 KB

  const int tid = threadIdx.x;
  const int wave = tid >> 6, lane = tid & 63;

  // staging: row tid>>2 (0..63), chunk slot tid&3; source chunk XOR-swizzled
  const int rS = tid >> 2, sS = tid & 3;
  const int swz = (sS ^ ((rS >> 1) & 3)) * 8;
  const bf16* gA;
  if (MODE == 0) gA = Ab + (size_t)tok[base + rS] * 1024 + swz;
  else           gA = Ab + (size_t)(base + rS) * 1024 + swz;
  const bf16* gB = Bp + (size_t)(n0 + rS) * 1024 + swz;
  const int dst8 = tid * 8;       // lane-contiguous 16B LDS dest

  const int wm = (wave >> 1) * 32, wn = (wave & 1) * 32;
  const int fr = lane & 15, chk = lane >> 4;
  int aOff[2], bOff[2];
#pragma unroll
  for (int i = 0; i < 2; i++) {
    const int r = wm + i * 16 + fr;
    aOff[i] = r * 32 + ((chk ^ ((r >> 1) & 3)) * 8);
  }
#pragma unroll
  for (int j = 0; j < 2; j++) {
    const int r = wn + j * 16 + fr;
    bOff[j] = r * 32 + ((chk ^ ((r >> 1) & 3)) * 8);
  }

  const f32x4 zero = {0.f, 0.f, 0.f, 0.f};
  f32x4 acc[2][2];
#pragma unroll
  for (int i = 0; i < 2; i++)
#pragma unroll
    for (int j = 0; j < 2; j++) acc[i][j] = zero;

  // prologue: tile 0 -> regs -> LDS[0]; tile 1 -> regs (in flight across barrier)
  uint4 rA = *(const uint4*)gA;
  uint4 rB = *(const uint4*)gB;
  *(uint4*)(As + dst8) = rA;
  *(uint4*)(Bs + dst8) = rB;
  rA = *(const uint4*)(gA + 32);
  rB = *(const uint4*)(gB + 32);
  __syncthreads();

  for (int kt = 0; kt < 32; ++kt) {
    const int cur = kt & 1;
    // publish tile kt+1 (regs loaded one iteration ago) into the free buffer
    if (kt + 1 < 32) {
      *(uint4*)(As + (cur ^ 1) * 2048 + dst8) = rA;
      *(uint4*)(Bs + (cur ^ 1) * 2048 + dst8) = rB;
    }
    // issue tile kt+2 loads; they fly across the barrier below
    if (kt + 2 < 32) {
      rA = *(const uint4*)(gA + (kt + 2) * 32);
      rB = *(const uint4*)(gB + (kt + 2) * 32);
    }
    bf16x8 af[2], bfv[2];
#pragma unroll
    for (int i = 0; i < 2; i++) af[i] = *(const bf16x8*)&As[cur * 2048 + aOff[i]];
#pragma unroll
    for (int j = 0; j < 2; j++) bfv[j] = *(const bf16x8*)&Bs[cur * 2048 + bOff[j]];
#pragma unroll
    for (int i = 0; i < 2; i++)
#pragma unroll
      for (int j = 0; j < 2; j++)
        acc[i][j] = __builtin_amdgcn_mfma_f32_16x16x32_bf16(af[i], bfv[j],
                                                            acc[i][j], 0, 0, 0);
    __syncthreads();  // lgkm only: ds_writes visible, reads of LDS[cur] done
  }

  const int rbase = (lane >> 4) * 4;
#pragma unroll
  for (int i = 0; i < 2; i++) {
#pragma unroll
    for (int j = 0; j < 2; j++) {
      const int col = n0 + wn + j * 16 + fr;
#pragma unroll
      for (int r = 0; r < 4; r++) {
        const int orow = wm + i * 16 + rbase + r;
        float v = acc[i][j][r];
        if (MODE == 0) v = v > 0.f ? v * v : 0.f;
        Cout[(size_t)(base + orow) * 1024 + col] = (bf16)v;
      }
    }
  }
}

// ---- combine: out[t] = w0*eo[s0] + w1*eo[s1] + eo[SB+t]. One block/token. ----
__global__ __launch_bounds__(256) void combine_kernel(
    const bf16* __restrict__ eo, const int* __restrict__ slotIdx,
    const float* __restrict__ wtok, float* __restrict__ out) {
  const int t = blockIdx.x;
  const int c = threadIdx.x * 4;
  const int s0 = slotIdx[t * 2], s1 = slotIdx[t * 2 + 1];
  const float w0 = wtok[t * 2], w1 = wtok[t * 2 + 1];
  union U { uint2 v; bf16 h[4]; };
  U a, b, sh;
  a.v  = *(const uint2*)(eo + (size_t)s0 * 1024 + c);
  b.v  = *(const uint2*)(eo + (size_t)s1 * 1024 + c);
  sh.v = *(const uint2*)(eo + (size_t)(SB + t) * 1024 + c);
  float4 o;
  o.x = w0 * (float)a.h[0] + w1 * (float)b.h[0] + (float)sh.h[0];
  o.y = w0 * (float)a.h[1] + w1 * (float)b.h[1] + (float)sh.h[1];
  o.z = w0 * (float)a.h[2] + w1 * (float)b.h[2] + (float)sh.h[2];
  o.w = w0 * (float)a.h[3] + w1 * (float)b.h[3] + (float)sh.h[3];
  *(float4*)(out + (size_t)t * 1024 + c) = o;
}

extern "C" void kernel_launch(void* const* d_in, const int* in_sizes, int n_in,
                              void* d_out, int out_size, void* d_ws,
                              size_t ws_size, hipStream_t stream) {
  const float* x     = (const float*)d_in[0];
  const float* gw    = (const float*)d_in[1];
  const float* lb    = (const float*)d_in[2];
  const float* w1    = (const float*)d_in[3];
  const float* w2    = (const float*)d_in[4];
  const float* cfc   = (const float*)d_in[5];
  const float* cproj = (const float*)d_in[6];
  float* out = (float*)d_out;
  char* ws = (char*)d_ws;

  int*   ntl   = (int*)(ws + WS_NTILES);
  int*   tE    = (int*)(ws + WS_TILE_E);
  int*   tB    = (int*)(ws + WS_TILE_BASE);
  int*   eidx  = (int*)(ws + WS_EIDX);
  float* wtok  = (float*)(ws + WS_WTOK);
  int*   tok   = (int*)(ws + WS_TOK);
  int*   slotI = (int*)(ws + WS_SLOT);
  bf16*  xg    = (bf16*)(ws + WS_XG);     // GEMM1 input; reused as eo for GEMM2 out
  bf16*  hid   = (bf16*)(ws + WS_HID);
  bf16*  w1b   = (bf16*)(ws + WS_W1B);
  bf16*  w2b   = (bf16*)(ws + WS_W2B);
  bf16*  cfcb  = (bf16*)(ws + WS_CFCB);
  bf16*  cprojb= (bf16*)(ws + WS_CPROJB);

  convrouter<<<9728, 256, 0, stream>>>(x, gw, lb, eidx, wtok, xg,
                                       w1, w2, cfc, cproj,
                                       w1b, w2b, cfcb, cprojb);
  assign_kernel<<<1, 256, 0, stream>>>(eidx, tE, tB, ntl, tok, slotI);

  moe_gemm<0><<<GEMM_GRID, 256, 0, stream>>>(
      xg, w1b, cfcb, tE, tB, ntl, hid, tok);
  moe_gemm<1><<<GEMM_GRID, 256, 0, stream>>>(
      hid, w2b, cprojb, tE, tB, ntl, xg, tok);
  combine_kernel<<<NTOK, 256, 0, stream>>>(xg, slotI, wtok, out);
}